// Round 4
// baseline (215.031 us; speedup 1.0000x reference)
//
#include <hip/hip_runtime.h>
#include <math.h>

#define EPSV 1e-4f
#define SCHUNK 64

typedef float f32x4 __attribute__((ext_vector_type(4)));  // clang-native: OK for nontemporal builtins

// Relaxed agent-scope atomics: point-wise LLC-coherent accesses (sc1), NO
// cache-wide invalidate/writeback (acquire/release would emit buffer_inv /
// buffer_wbl2 on gfx950 since per-XCD L2s are non-coherent -> catastrophic).
// Ordering is done manually with s_waitcnt vmcnt(0) before flag stores.
__device__ __forceinline__ float agent_load_f(const float* p) {
    return __hip_atomic_load(p, __ATOMIC_RELAXED, __HIP_MEMORY_SCOPE_AGENT);
}
__device__ __forceinline__ void agent_store_f(float* p, float v) {
    __hip_atomic_store(p, v, __ATOMIC_RELAXED, __HIP_MEMORY_SCOPE_AGENT);
}
__device__ __forceinline__ int agent_load_i(const int* p) {
    return __hip_atomic_load(p, __ATOMIC_RELAXED, __HIP_MEMORY_SCOPE_AGENT);
}
__device__ __forceinline__ void agent_store_i(int* p, int v) {
    __hip_atomic_store(p, v, __ATOMIC_RELAXED, __HIP_MEMORY_SCOPE_AGENT);
}
__device__ __forceinline__ f32x4 agent_load_f4(const float* p) {
    f32x4 r;
    r.x = agent_load_f(p + 0);
    r.y = agent_load_f(p + 1);
    r.z = agent_load_f(p + 2);
    r.w = agent_load_f(p + 3);
    return r;
}

// ---------------- clear: all flags + ticket (one launch) ----------------
__global__ void clear_kernel(int* __restrict__ flags, int n) {
    int i = blockIdx.x * blockDim.x + threadIdx.x;
    if (i < n) flags[i] = 0;
}

// ---------------- fused b_flat scan -> sidx (single kernel) ----------------
// 256 blocks x 256 threads, 1024 b-elements per block.
// Block-level decoupled sum: publish block sum + flag; then thread i (< bid)
// spins on flags2[i] and loads bsum[i] IN PARALLEL, LDS tree-reduce -> offset.
// O(1) lookback depth, no serial chain. Deadlock-free: publish before wait.
__global__ __launch_bounds__(256) void sidx_kernel(
        const int* __restrict__ b, int n,
        int* __restrict__ bsum,
        int* __restrict__ flags2,
        int* __restrict__ sidx, int L, int Louter) {
    __shared__ int red[256];
    __shared__ int red2[256];
    const int tid = threadIdx.x;
    const int bid = blockIdx.x;
    const int base = bid * 1024 + tid * 4;

    int v[4];
    int s = 0;
#pragma unroll
    for (int k = 0; k < 4; ++k) {
        int j = base + k;
        v[k] = (j < n) ? b[j] : 0;
        s += v[k];
    }
    red[tid] = s;
    __syncthreads();
    // inclusive block scan (Hillis-Steele)
    for (int off = 1; off < 256; off <<= 1) {
        int t = red[tid];
        if (tid >= off) t += red[tid - off];
        __syncthreads();
        red[tid] = t;
        __syncthreads();
    }
    // publish block sum
    if (tid == 255) {
        agent_store_i(&bsum[bid], red[255]);
        asm volatile("s_waitcnt vmcnt(0)" ::: "memory");
        agent_store_i(&flags2[bid], 1);
    }
    // parallel lookback: thread i < bid grabs predecessor i's sum
    int mysum = 0;
    if (tid < bid) {
        while (agent_load_i(&flags2[tid]) == 0) __builtin_amdgcn_s_sleep(1);
        mysum = agent_load_i(&bsum[tid]);
    }
    red2[tid] = mysum;
    __syncthreads();
    for (int off = 128; off > 0; off >>= 1) {
        if (tid < off) red2[tid] += red2[tid + off];
        __syncthreads();
    }
    const int boff = red2[0];   // exclusive global prefix of this block

    // emit: sidx[t] = first out-row j of timestep t
    int cum = red[tid] - s + boff;
#pragma unroll
    for (int k = 0; k < 4; ++k) {
        int j = base + k;
        if (j < n) {
            cum += v[k];
            if (v[k] > 0) {
                int t = cum - 1;
                if (t >= 0 && t < L) sidx[t] = j;
            }
        }
    }
    if (tid == 0 && bid == 0) sidx[L] = Louter;
}

// ---------------- single-pass decoupled-lookback scan + scatter ----------------
// blockDim.x == d/4 (128): one thread owns 4 channels (f32x4, 16 B/lane).
// SCHUNK=64 timesteps per block. Pass 1: aggregate-only local scan (no z[]).
// Pass 2: re-read h (L2/LLC-hot) and rescan with carry folded in, scattering
// f32x4 directly to out. Thread 0 alone spins on predecessor flags.
// Deadlock-free: ticket => predecessors resident; flags published before wait.
__global__ __launch_bounds__(128, 4) void scan_lookback_kernel(
        const float* __restrict__ h,
        const float* __restrict__ psel,
        const int* __restrict__ seq,
        const int* __restrict__ sidx,
        float* __restrict__ out,
        float* __restrict__ aggE,   // [NC][d]
        float* __restrict__ aggP,   // [NC]
        int* __restrict__ flags,    // [NC] flags, flags[NC] = ticket
        int L, int d, int Louter, int NC) {
    __shared__ float sh_a[SCHUNK];
    __shared__ float sh_p[SCHUNK];
    __shared__ int   sh_j[SCHUNK + 1];
    __shared__ int   sh_g;
    __shared__ float sh_Pown;
    __shared__ float sh_Pbr;

    const int tid = threadIdx.x;
    if (tid == 0) sh_g = atomicAdd(&flags[NC], 1);  // device-scope ticket
    __syncthreads();
    const int g  = sh_g;
    const int t0 = g * SCHUNK;
    const int nt = min(SCHUNK, L - t0);

    // prologue: per-timestep scalars (fused prep) + scatter ranges into LDS
    if (tid < nt) {
        int t = t0 + tid;
        float p = psel[t];
        p = fminf(fmaxf(p, EPSV), 1.0f - EPSV);
        bool start = (t == 0) || (seq[t] != seq[t - 1]);
        sh_a[tid] = start ? 0.0f : (1.0f - p);   // exp(-dt) == 1-p exactly
        sh_p[tid] = p;                           // b_t = p*h
    }
    if (tid <= nt) sh_j[tid] = sidx[t0 + tid];   // sidx[L] sentinel exists
    __syncthreads();

    // chunk decay product P = prod(a) via wave-0 butterfly
    if (tid < 64) {
        float v = (tid < nt) ? sh_a[tid] : 1.0f;
#pragma unroll
        for (int m = 1; m < 64; m <<= 1) v *= __shfl_xor(v, m);
        if (tid == 0) sh_Pown = v;
    }

    const int c0 = tid * 4;
    const float* __restrict__ hp = h + (size_t)t0 * d + c0;

    // ---- pass 1: aggregate-only local scan (zero init) ----
    f32x4 st = {0.f, 0.f, 0.f, 0.f};
    const bool full = (nt == SCHUNK);
    if (full) {
#pragma unroll
        for (int grp = 0; grp < SCHUNK / 8; ++grp) {
            f32x4 hb[8];
#pragma unroll
            for (int k = 0; k < 8; ++k)
                hb[k] = *(const f32x4*)(hp + (size_t)(grp * 8 + k) * d);
#pragma unroll
            for (int k = 0; k < 8; ++k) {
                int t = grp * 8 + k;
                float at = sh_a[t], pt = sh_p[t];
                st.x = fmaf(at, st.x, pt * hb[k].x);
                st.y = fmaf(at, st.y, pt * hb[k].y);
                st.z = fmaf(at, st.z, pt * hb[k].z);
                st.w = fmaf(at, st.w, pt * hb[k].w);
            }
        }
    } else {
        for (int t = 0; t < nt; ++t) {
            f32x4 h4 = *(const f32x4*)(hp + (size_t)t * d);
            float at = sh_a[t], pt = sh_p[t];
            st.x = fmaf(at, st.x, pt * h4.x);
            st.y = fmaf(at, st.y, pt * h4.y);
            st.z = fmaf(at, st.z, pt * h4.z);
            st.w = fmaf(at, st.w, pt * h4.w);
        }
    }

    // ---- publish aggregate (relaxed + waitcnt ordering) ----
    float* ep = aggE + (size_t)g * d + c0;
    agent_store_f(ep + 0, st.x);
    agent_store_f(ep + 1, st.y);
    agent_store_f(ep + 2, st.z);
    agent_store_f(ep + 3, st.w);
    __syncthreads();            // every wave drains vmcnt before the barrier
    if (tid == 0) {
        agent_store_f(&aggP[g], sh_Pown);
        asm volatile("s_waitcnt vmcnt(0)" ::: "memory");  // aggP before flag
        agent_store_i(&flags[g], 1);
    }

    // ---- decoupled lookback: carry = state at end of chunk g-1 ----
    f32x4 carry = {0.f, 0.f, 0.f, 0.f};
    float prodAcc = 1.0f;
    for (int i = g - 1; i >= 0; --i) {
        if (tid == 0) {
            while (agent_load_i(&flags[i]) == 0) __builtin_amdgcn_s_sleep(1);
            sh_Pbr = agent_load_f(&aggP[i]);
        }
        __syncthreads();
        float Pi = sh_Pbr;
        f32x4 E = agent_load_f4(aggE + (size_t)i * d + c0);
        carry.x = fmaf(prodAcc, E.x, carry.x);
        carry.y = fmaf(prodAcc, E.y, carry.y);
        carry.z = fmaf(prodAcc, E.z, carry.z);
        carry.w = fmaf(prodAcc, E.w, carry.w);
        prodAcc *= Pi;                    // uniform across threads
        __syncthreads();                  // sh_Pbr reused next iteration
        if (prodAcc == 0.0f) break;       // decay underflow / seq reset (~2 steps)
    }

    // ---- pass 2: rescan with carry folded in, scatter f32x4 to out ----
    f32x4 s2 = carry;
    if (full) {
#pragma unroll
        for (int grp = 0; grp < SCHUNK / 8; ++grp) {
            f32x4 hb[8];
#pragma unroll
            for (int k = 0; k < 8; ++k)
                hb[k] = *(const f32x4*)(hp + (size_t)(grp * 8 + k) * d);  // L2/LLC hit
#pragma unroll
            for (int k = 0; k < 8; ++k) {
                int t = grp * 8 + k;
                float at = sh_a[t], pt = sh_p[t];
                s2.x = fmaf(at, s2.x, pt * hb[k].x);
                s2.y = fmaf(at, s2.y, pt * hb[k].y);
                s2.z = fmaf(at, s2.z, pt * hb[k].z);
                s2.w = fmaf(at, s2.w, pt * hb[k].w);
                int j0 = max(sh_j[t], 0);
                int j1 = min(sh_j[t + 1], Louter);
                for (int j = j0; j < j1; ++j)
                    __builtin_nontemporal_store(s2, (f32x4*)(out + (size_t)j * d + c0));
            }
        }
    } else {
        for (int t = 0; t < nt; ++t) {
            f32x4 h4 = *(const f32x4*)(hp + (size_t)t * d);
            float at = sh_a[t], pt = sh_p[t];
            s2.x = fmaf(at, s2.x, pt * h4.x);
            s2.y = fmaf(at, s2.y, pt * h4.y);
            s2.z = fmaf(at, s2.z, pt * h4.z);
            s2.w = fmaf(at, s2.w, pt * h4.w);
            int j0 = max(sh_j[t], 0);
            int j1 = min(sh_j[t + 1], Louter);
            for (int j = j0; j < j1; ++j)
                *(f32x4*)(out + (size_t)j * d + c0) = s2;
        }
    }
}

extern "C" void kernel_launch(void* const* d_in, const int* in_sizes, int n_in,
                              void* d_out, int out_size, void* d_ws, size_t ws_size,
                              hipStream_t stream) {
    const float* h     = (const float*)d_in[0];
    const int*   bflat = (const int*)d_in[1];
    const float* psel  = (const float*)d_in[2];
    const int*   seq   = (const int*)d_in[3];
    float* out = (float*)d_out;

    const int L      = in_sizes[2];          // 131072
    const int Louter = in_sizes[1];          // 262144
    const int d      = in_sizes[0] / L;      // 512 (divisible by 4)

    const int NC = (L + SCHUNK - 1) / SCHUNK;   // 2048
    const int nb = (Louter + 1023) / 1024;      // 256 scan blocks

    // workspace layout (256B-aligned slices) — total ~4.6 MB
    char* ws = (char*)d_ws;
    size_t off = 0;
    auto alloc = [&](size_t bytes) -> void* {
        void* p = ws + off;
        off = (off + bytes + 255) & ~(size_t)255;
        return p;
    };
    float* aggE   = (float*)alloc((size_t)NC * d * 4);
    float* aggP   = (float*)alloc((size_t)NC * 4);
    int*   flags  = (int*)alloc((size_t)(NC + 1 + nb) * 4);  // [NC]=ticket, then flags2
    int*   bsum   = (int*)alloc((size_t)nb * 4);
    int*   sidx   = (int*)alloc((size_t)(L + 1) * 4);
    int*   flags2 = flags + NC + 1;
    (void)ws_size;

    clear_kernel<<<(NC + 1 + nb + 255) / 256, 256, 0, stream>>>(flags, NC + 1 + nb);

    sidx_kernel<<<nb, 256, 0, stream>>>(bflat, Louter, bsum, flags2, sidx, L, Louter);

    scan_lookback_kernel<<<NC, d / 4, 0, stream>>>(h, psel, seq, sidx, out,
                                                   aggE, aggP, flags,
                                                   L, d, Louter, NC);
}